// Round 4
// baseline (592.976 us; speedup 1.0000x reference)
//
#include <hip/hip_runtime.h>

// VoxelHashTable R4 (= R3 with compile fix: nontemporal stores need native
// vector types, not HIP_vector_type<float,4>).
//
// Spatial binning + dense pre-resolved hash tables:
//   Pass A (build_dense): dense[(ix,iy,iz)] = h2v[hash(ix,iy,iz)] for all
//     voxel coords reachable by query corners (exactly reproduces collisions);
//     also zeros the cell histogram.
//   Pass B (count_cells): cell id per query (0.96^3 cells) + histogram.
//   Pass C (scan_hist):   exclusive scan of 448 cell counts (1 block).
//   Pass D (scatter):     qsorted[pos] = (x,y,z, bitcast(query_idx)).
//   Pass E (main):        8 threads per (sorted-query, level) group; corner
//     lookups hit the small dense tables; feats gathers are cell-local ->
//     L2-resident; XCD swizzle (blockIdx%8 chunking) keeps each feats row on
//     ~one XCD; output stored nontemporally (125 MB stream, don't evict L2).

#define TMASK 0xFFFFFu   // TSIZE = 2^20 -> '&' == jnp.mod (floored)
#define PM0 455773u      // 73856093 % 2^20
#define PM1 475301u      // 19349669 % 2^20
#define PM2 655287u      // 83492791 % 2^20

#define BMINX -2.6f
#define BMINY -8.1f
#define BMINZ  0.0f
#define BMAXX  4.6f
#define BMAXY  4.7f
#define BMAXZ  3.1f
#define RES0   0.12f
#define RES1   0.24f

#define CELL 0.96f
#define NCX  8
#define NCY  14
#define NCZ  4
#define NC   (NCX * NCY * NCZ)   // 448 (<= 512 for the 1-block scan)

typedef float  nfloat4 __attribute__((ext_vector_type(4)));  // native vec4

static __device__ __forceinline__ unsigned vhash(int cx, int cy, int cz) {
    return ((unsigned)cx * PM0 + (unsigned)cy * PM1 + (unsigned)cz * PM2) & TMASK;
}

// ---- Pass A: dense voxel-index tables (+ histogram zero) -------------------
__global__ __launch_bounds__(256) void build_dense(
    const int* __restrict__ h2v0, const int* __restrict__ h2v1,
    int* __restrict__ dense0, int* __restrict__ dense1,
    int x0a, int y0a, int z0a, int eya, int eza,
    int x0b, int y0b, int z0b, int eyb, int ezb,
    int D0, int D1, int* __restrict__ hist)
{
    const int i = blockIdx.x * blockDim.x + threadIdx.x;
    if (i < NC) hist[i] = 0;
    if (i < D0) {
        const int iz = i % eza, t = i / eza, iy = t % eya, ix = t / eya;
        dense0[i] = h2v0[vhash(ix + x0a, iy + y0a, iz + z0a)];
    } else if (i < D0 + D1) {
        const int j = i - D0;
        const int iz = j % ezb, t = j / ezb, iy = t % eyb, ix = t / eyb;
        dense1[j] = h2v1[vhash(ix + x0b, iy + y0b, iz + z0b)];
    }
}

// ---- Pass B: cell id + histogram ------------------------------------------
__global__ __launch_bounds__(256) void count_cells(
    const float* __restrict__ qpts, int* __restrict__ cellid,
    int* __restrict__ hist, int M)
{
    const int q = blockIdx.x * blockDim.x + threadIdx.x;
    if (q >= M) return;
    const float x = qpts[3 * (size_t)q + 0];
    const float y = qpts[3 * (size_t)q + 1];
    const float z = qpts[3 * (size_t)q + 2];
    int cx = (int)floorf((x - BMINX) / CELL);
    int cy = (int)floorf((y - BMINY) / CELL);
    int cz = (int)floorf((z - BMINZ) / CELL);
    cx = min(max(cx, 0), NCX - 1);
    cy = min(max(cy, 0), NCY - 1);
    cz = min(max(cz, 0), NCZ - 1);
    const int c = (cx * NCY + cy) * NCZ + cz;
    cellid[q] = c;
    atomicAdd(&hist[c], 1);
}

// ---- Pass C: exclusive scan over NC<=512 cells (single block) -------------
__global__ __launch_bounds__(512) void scan_hist(
    const int* __restrict__ hist, int* __restrict__ offs)
{
    __shared__ int s[512];
    const int t = threadIdx.x;
    const int v = (t < NC) ? hist[t] : 0;
    s[t] = v;
    __syncthreads();
    for (int d = 1; d < 512; d <<= 1) {
        const int a = (t >= d) ? s[t - d] : 0;
        __syncthreads();
        s[t] += a;
        __syncthreads();
    }
    if (t < NC) offs[t] = s[t] - v;   // exclusive
}

// ---- Pass D: scatter queries into sorted order ----------------------------
__global__ __launch_bounds__(256) void scatter_queries(
    const float* __restrict__ qpts, const int* __restrict__ cellid,
    int* __restrict__ offs, nfloat4* __restrict__ qsorted, int M)
{
    const int q = blockIdx.x * blockDim.x + threadIdx.x;
    if (q >= M) return;
    const int pos = atomicAdd(&offs[cellid[q]], 1);
    nfloat4 v;
    v.x = qpts[3 * (size_t)q + 0];
    v.y = qpts[3 * (size_t)q + 1];
    v.z = qpts[3 * (size_t)q + 2];
    v.w = __int_as_float(q);
    __builtin_nontemporal_store(v, &qsorted[pos]);
}

// ---- Pass E: main query kernel --------------------------------------------
__global__ __launch_bounds__(256) void voxel_query_sorted(
    const nfloat4* __restrict__ qsorted,
    const float*  __restrict__ feats0, const float* __restrict__ feats1,
    const int*    __restrict__ h2v0,   const int*   __restrict__ h2v1,
    const int*    __restrict__ dense0, const int*   __restrict__ dense1,
    int x0a, int y0a, int z0a, int exa, int eya, int eza,
    int x0b, int y0b, int z0b, int exb, int eyb, int ezb,
    float* __restrict__ out, int M, int nb)
{
    // XCD swizzle: blocks with equal (blockIdx%8) cover a contiguous chunk of
    // the sorted query order (heuristic: blockIdx%8 ~ XCD id). Bijection over
    // the padded grid; lb >= nb blocks idle.
    const int nb8 = (nb + 7) >> 3;
    const int lb  = ((int)blockIdx.x & 7) * nb8 + ((int)blockIdx.x >> 3);
    if (lb >= nb) return;

    const int g  = lb * 32 + ((int)threadIdx.x >> 3);  // (sorted query, level)
    const int gt = (int)threadIdx.x & 7;               // corner / chunk idx
    const int s  = g >> 1;
    const int level = g & 1;
    if (s >= M) return;

    const nfloat4 q4 = qsorted[s];
    const int qi = __float_as_int(q4.w);

    const float res = level ? RES1 : RES0;
    const float* __restrict__ feats = level ? feats1 : feats0;
    const int*   __restrict__ h2v   = level ? h2v1   : h2v0;
    const int*   __restrict__ dense = level ? dense1 : dense0;
    const int x0 = level ? x0b : x0a, y0 = level ? y0b : y0a, z0 = level ? z0b : z0a;
    const int ex = level ? exb : exa, ey = level ? eyb : eya, ez = level ? ezb : eza;

    // exact f32 division to match reference floor/frac bitwise
    const float sx = q4.x / res, sy = q4.y / res, sz = q4.z / res;
    const float bx = floorf(sx), by = floorf(sy), bz = floorf(sz);
    const float fx = sx - bx,  fy = sy - by,  fz = sz - bz;

    const int ox = (gt >> 2) & 1, oy = (gt >> 1) & 1, oz = gt & 1;
    const int cx = (int)bx + ox;
    const int cy = (int)by + oy;
    const int cz = (int)bz + oz;

    int v;
    if (cx >= x0 && cx < x0 + ex && cy >= y0 && cy < y0 + ey &&
        cz >= z0 && cz < z0 + ez) {
        v = dense[((size_t)(cx - x0) * ey + (cy - y0)) * ez + (cz - z0)];
    } else {
        v = h2v[vhash(cx, cy, cz)];   // margin makes this ~never taken
    }

    float w = (ox ? fx : 1.0f - fx) * (oy ? fy : 1.0f - fy);
    w *= (oz ? fz : 1.0f - fz);

    nfloat4 acc = {0.0f, 0.0f, 0.0f, 0.0f};
    #pragma unroll
    for (int c = 0; c < 8; ++c) {
        const int   vc = __shfl(v, c, 8);
        const float wc = __shfl(w, c, 8);
        if (vc >= 0) {   // uniform within the 8-lane group
            const nfloat4 f4 = ((const nfloat4*)(feats + (size_t)vc * 32))[gt];
            acc += wc * f4;
        }
    }

    // streaming store: don't evict feats from L2
    __builtin_nontemporal_store(
        acc, (nfloat4*)(out + (size_t)qi * 64 + level * 32) + gt);
}

// ---- fallback: direct (unsorted) f32 kernel --------------------------------
__global__ __launch_bounds__(256) void voxel_hash_query_f32(
    const float* __restrict__ qpts,
    const float* __restrict__ feats0, const float* __restrict__ feats1,
    const int*   __restrict__ h2v0,   const int*   __restrict__ h2v1,
    float* __restrict__ out, int M)
{
    const int tid = blockIdx.x * blockDim.x + threadIdx.x;
    const int group = tid >> 3, gt = tid & 7;
    const int m = group >> 1, level = group & 1;
    if (m >= M) return;
    const float res = level ? RES1 : RES0;
    const float* __restrict__ feats = level ? feats1 : feats0;
    const int*   __restrict__ h2v   = level ? h2v1   : h2v0;
    const float qx = qpts[3 * (size_t)m], qy = qpts[3 * (size_t)m + 1],
                qz = qpts[3 * (size_t)m + 2];
    const float sx = qx / res, sy = qy / res, sz = qz / res;
    const float bx = floorf(sx), by = floorf(sy), bz = floorf(sz);
    const float fx = sx - bx, fy = sy - by, fz = sz - bz;
    const int ox = (gt >> 2) & 1, oy = (gt >> 1) & 1, oz = gt & 1;
    const int v = h2v[vhash((int)bx + ox, (int)by + oy, (int)bz + oz)];
    float w = (ox ? fx : 1.0f - fx) * (oy ? fy : 1.0f - fy);
    w *= (oz ? fz : 1.0f - fz);
    nfloat4 acc = {0.f, 0.f, 0.f, 0.f};
    #pragma unroll
    for (int c = 0; c < 8; ++c) {
        const int vc = __shfl(v, c, 8);
        const float wc = __shfl(w, c, 8);
        if (vc >= 0) {
            const nfloat4 f4 = ((const nfloat4*)(feats + (size_t)vc * 32))[gt];
            acc += wc * f4;
        }
    }
    ((nfloat4*)(out + (size_t)m * 64 + level * 32))[gt] = acc;
}

extern "C" void kernel_launch(void* const* d_in, const int* in_sizes, int n_in,
                              void* d_out, int out_size, void* d_ws, size_t ws_size,
                              hipStream_t stream) {
    const float* qpts   = (const float*)d_in[0];
    const float* feats0 = (const float*)d_in[1];
    const float* feats1 = (const float*)d_in[2];
    const int*   h2v0   = (const int*)d_in[3];
    const int*   h2v1   = (const int*)d_in[4];
    float* out = (float*)d_out;
    const int M = in_sizes[0] / 3;

    // dense-table bounds per level (margin 2 beyond any reachable corner)
    const float bmin[3] = {BMINX, BMINY, BMINZ};
    const float bmax[3] = {BMAXX, BMAXY, BMAXZ};
    int lo0[3], ex0[3], lo1[3], ex1[3];
    for (int d = 0; d < 3; ++d) {
        lo0[d] = (int)floorf(bmin[d] / RES0) - 2;
        ex0[d] = (int)floorf(bmax[d] / RES0) + 3 - lo0[d] + 1;
        lo1[d] = (int)floorf(bmin[d] / RES1) - 2;
        ex1[d] = (int)floorf(bmax[d] / RES1) + 3 - lo1[d] + 1;
    }
    const int D0 = ex0[0] * ex0[1] * ex0[2];
    const int D1 = ex1[0] * ex1[1] * ex1[2];

    // workspace layout (qsorted first for 16B alignment)
    char* p = (char*)d_ws;
    nfloat4* qsorted = (nfloat4*)p;        p += (size_t)M * 16;
    int* dense0 = (int*)p;                 p += (size_t)D0 * 4;
    int* dense1 = (int*)p;                 p += (size_t)D1 * 4;
    int* cellid = (int*)p;                 p += (size_t)M * 4;
    int* hist   = (int*)p;                 p += (size_t)NC * 4;
    int* offs   = (int*)p;                 p += (size_t)NC * 4;
    const size_t need = (size_t)(p - (char*)d_ws);

    const long long threads_needed = 16LL * M;
    const int nb = (int)((threads_needed + 255) / 256);

    if (ws_size < need) {
        voxel_hash_query_f32<<<nb, 256, 0, stream>>>(qpts, feats0, feats1,
                                                     h2v0, h2v1, out, M);
        return;
    }

    const int gA = (D0 + D1 + 255) / 256;
    build_dense<<<gA, 256, 0, stream>>>(h2v0, h2v1, dense0, dense1,
                                        lo0[0], lo0[1], lo0[2], ex0[1], ex0[2],
                                        lo1[0], lo1[1], lo1[2], ex1[1], ex1[2],
                                        D0, D1, hist);

    const int gQ = (M + 255) / 256;
    count_cells<<<gQ, 256, 0, stream>>>(qpts, cellid, hist, M);
    scan_hist<<<1, 512, 0, stream>>>(hist, offs);
    scatter_queries<<<gQ, 256, 0, stream>>>(qpts, cellid, offs, qsorted, M);

    const int nb8 = (nb + 7) / 8;
    voxel_query_sorted<<<nb8 * 8, 256, 0, stream>>>(
        qsorted, feats0, feats1, h2v0, h2v1, dense0, dense1,
        lo0[0], lo0[1], lo0[2], ex0[0], ex0[1], ex0[2],
        lo1[0], lo1[1], lo1[2], ex1[0], ex1[1], ex1[2],
        out, M, nb);
}

// Round 5
// 273.529 us; speedup vs baseline: 2.1679x; 2.1679x over previous
//
#include <hip/hip_runtime.h>

// VoxelHashTable R5: R4 with the binning bookkeeping fixed.
//   - hist/offs counters padded to one per 128B cache line (448 lines, not 14)
//   - count/scatter LDS-aggregate 2048 queries/block: per-block ranks from LDS
//     atomics, ONE global atomicAdd per (block, cell) to reserve a range.
//   - cellid array dropped (recomputed; coords held in registers).
// Main kernel (sorted queries + dense pre-resolved hash tables + XCD swizzle
// + nontemporal full-line output stores) unchanged from R4.

#define TMASK 0xFFFFFu   // TSIZE = 2^20 -> '&' == jnp.mod (floored)
#define PM0 455773u      // 73856093 % 2^20
#define PM1 475301u      // 19349669 % 2^20
#define PM2 655287u      // 83492791 % 2^20

#define BMINX -2.6f
#define BMINY -8.1f
#define BMINZ  0.0f
#define BMAXX  4.6f
#define BMAXY  4.7f
#define BMAXZ  3.1f
#define RES0   0.12f
#define RES1   0.24f

#define CELL 0.96f
#define NCX  8
#define NCY  14
#define NCZ  4
#define NC   (NCX * NCY * NCZ)   // 448 (<= 512 for the 1-block scan)
#define CPAD 32                  // ints per counter slot = 128B line
#define QPB  2048                // queries per block in binning passes
#define QPT  (QPB / 256)         // 8 queries per thread

typedef float nfloat4 __attribute__((ext_vector_type(4)));  // native vec4

static __device__ __forceinline__ unsigned vhash(int cx, int cy, int cz) {
    return ((unsigned)cx * PM0 + (unsigned)cy * PM1 + (unsigned)cz * PM2) & TMASK;
}

static __device__ __forceinline__ int cell_of(float x, float y, float z) {
    int cx = (int)floorf((x - BMINX) / CELL);
    int cy = (int)floorf((y - BMINY) / CELL);
    int cz = (int)floorf((z - BMINZ) / CELL);
    cx = min(max(cx, 0), NCX - 1);
    cy = min(max(cy, 0), NCY - 1);
    cz = min(max(cz, 0), NCZ - 1);
    return (cx * NCY + cy) * NCZ + cz;
}

// ---- Pass A: dense voxel-index tables (+ zero padded histogram) ------------
__global__ __launch_bounds__(256) void build_dense(
    const int* __restrict__ h2v0, const int* __restrict__ h2v1,
    int* __restrict__ dense0, int* __restrict__ dense1,
    int x0a, int y0a, int z0a, int eya, int eza,
    int x0b, int y0b, int z0b, int eyb, int ezb,
    int D0, int D1, int* __restrict__ hist)
{
    const int i = blockIdx.x * blockDim.x + threadIdx.x;
    if (i < NC * CPAD) hist[i] = 0;
    if (i < D0) {
        const int iz = i % eza, t = i / eza, iy = t % eya, ix = t / eya;
        dense0[i] = h2v0[vhash(ix + x0a, iy + y0a, iz + z0a)];
    } else if (i < D0 + D1) {
        const int j = i - D0;
        const int iz = j % ezb, t = j / ezb, iy = t % eyb, ix = t / eyb;
        dense1[j] = h2v1[vhash(ix + x0b, iy + y0b, iz + z0b)];
    }
}

// ---- Pass B: histogram (LDS-aggregated, padded global counters) -----------
__global__ __launch_bounds__(256) void count_cells(
    const float* __restrict__ qpts, int* __restrict__ hist, int M)
{
    __shared__ int lh[NC];
    for (int i = threadIdx.x; i < NC; i += 256) lh[i] = 0;
    __syncthreads();
    const int base = blockIdx.x * QPB;
    #pragma unroll
    for (int k = 0; k < QPT; ++k) {
        const int q = base + k * 256 + threadIdx.x;
        if (q < M) {
            const float x = qpts[3 * (size_t)q + 0];
            const float y = qpts[3 * (size_t)q + 1];
            const float z = qpts[3 * (size_t)q + 2];
            atomicAdd(&lh[cell_of(x, y, z)], 1);
        }
    }
    __syncthreads();
    for (int i = threadIdx.x; i < NC; i += 256) {
        const int v = lh[i];
        if (v) atomicAdd(&hist[i * CPAD], v);
    }
}

// ---- Pass C: exclusive scan over NC<=512 cells (single block) -------------
__global__ __launch_bounds__(512) void scan_hist(
    const int* __restrict__ hist, int* __restrict__ offs)
{
    __shared__ int s[512];
    const int t = threadIdx.x;
    const int v = (t < NC) ? hist[t * CPAD] : 0;
    s[t] = v;
    __syncthreads();
    for (int d = 1; d < 512; d <<= 1) {
        const int a = (t >= d) ? s[t - d] : 0;
        __syncthreads();
        s[t] += a;
        __syncthreads();
    }
    if (t < NC) offs[t * CPAD] = s[t] - v;   // exclusive
}

// ---- Pass D: scatter (per-block range reservation) ------------------------
__global__ __launch_bounds__(256) void scatter_queries(
    const float* __restrict__ qpts, int* __restrict__ offs,
    nfloat4* __restrict__ qsorted, int M)
{
    __shared__ int lh[NC];     // per-block per-cell count / rank counter
    __shared__ int lbase[NC];  // per-block per-cell global base
    for (int i = threadIdx.x; i < NC; i += 256) lh[i] = 0;
    __syncthreads();

    const int base = blockIdx.x * QPB;
    float qx[QPT], qy[QPT], qz[QPT];
    int   qc[QPT], qr[QPT];
    #pragma unroll
    for (int k = 0; k < QPT; ++k) {
        const int q = base + k * 256 + threadIdx.x;
        if (q < M) {
            qx[k] = qpts[3 * (size_t)q + 0];
            qy[k] = qpts[3 * (size_t)q + 1];
            qz[k] = qpts[3 * (size_t)q + 2];
            qc[k] = cell_of(qx[k], qy[k], qz[k]);
            qr[k] = atomicAdd(&lh[qc[k]], 1);      // rank within block
        } else qc[k] = -1;
    }
    __syncthreads();
    for (int i = threadIdx.x; i < NC; i += 256) {
        const int v = lh[i];
        if (v) lbase[i] = atomicAdd(&offs[i * CPAD], v);  // reserve range
    }
    __syncthreads();
    #pragma unroll
    for (int k = 0; k < QPT; ++k) {
        if (qc[k] >= 0) {
            const int pos = lbase[qc[k]] + qr[k];
            nfloat4 v = {qx[k], qy[k], qz[k],
                         __int_as_float(base + k * 256 + threadIdx.x)};
            __builtin_nontemporal_store(v, &qsorted[pos]);
        }
    }
}

// ---- Pass E: main query kernel --------------------------------------------
__global__ __launch_bounds__(256) void voxel_query_sorted(
    const nfloat4* __restrict__ qsorted,
    const float*  __restrict__ feats0, const float* __restrict__ feats1,
    const int*    __restrict__ h2v0,   const int*   __restrict__ h2v1,
    const int*    __restrict__ dense0, const int*   __restrict__ dense1,
    int x0a, int y0a, int z0a, int exa, int eya, int eza,
    int x0b, int y0b, int z0b, int exb, int eyb, int ezb,
    float* __restrict__ out, int M, int nb)
{
    // XCD swizzle: blocks with equal (blockIdx%8) cover a contiguous chunk of
    // the sorted query order. Bijection over the padded grid; lb>=nb idle.
    const int nb8 = (nb + 7) >> 3;
    const int lb  = ((int)blockIdx.x & 7) * nb8 + ((int)blockIdx.x >> 3);
    if (lb >= nb) return;

    const int g  = lb * 32 + ((int)threadIdx.x >> 3);  // (sorted query, level)
    const int gt = (int)threadIdx.x & 7;               // corner / chunk idx
    const int s  = g >> 1;
    const int level = g & 1;
    if (s >= M) return;

    const nfloat4 q4 = qsorted[s];
    const int qi = __float_as_int(q4.w);

    const float res = level ? RES1 : RES0;
    const float* __restrict__ feats = level ? feats1 : feats0;
    const int*   __restrict__ h2v   = level ? h2v1   : h2v0;
    const int*   __restrict__ dense = level ? dense1 : dense0;
    const int x0 = level ? x0b : x0a, y0 = level ? y0b : y0a, z0 = level ? z0b : z0a;
    const int ex = level ? exb : exa, ey = level ? eyb : eya, ez = level ? ezb : eza;

    // exact f32 division to match reference floor/frac bitwise
    const float sx = q4.x / res, sy = q4.y / res, sz = q4.z / res;
    const float bx = floorf(sx), by = floorf(sy), bz = floorf(sz);
    const float fx = sx - bx,  fy = sy - by,  fz = sz - bz;

    const int ox = (gt >> 2) & 1, oy = (gt >> 1) & 1, oz = gt & 1;
    const int cx = (int)bx + ox;
    const int cy = (int)by + oy;
    const int cz = (int)bz + oz;

    int v;
    if (cx >= x0 && cx < x0 + ex && cy >= y0 && cy < y0 + ey &&
        cz >= z0 && cz < z0 + ez) {
        v = dense[((size_t)(cx - x0) * ey + (cy - y0)) * ez + (cz - z0)];
    } else {
        v = h2v[vhash(cx, cy, cz)];   // margin makes this ~never taken
    }

    float w = (ox ? fx : 1.0f - fx) * (oy ? fy : 1.0f - fy);
    w *= (oz ? fz : 1.0f - fz);

    nfloat4 acc = {0.0f, 0.0f, 0.0f, 0.0f};
    #pragma unroll
    for (int c = 0; c < 8; ++c) {
        const int   vc = __shfl(v, c, 8);
        const float wc = __shfl(w, c, 8);
        if (vc >= 0) {   // uniform within the 8-lane group
            const nfloat4 f4 = ((const nfloat4*)(feats + (size_t)vc * 32))[gt];
            acc += wc * f4;
        }
    }

    // full-line (128B/group) streaming store: don't evict feats from L2
    __builtin_nontemporal_store(
        acc, (nfloat4*)(out + (size_t)qi * 64 + level * 32) + gt);
}

// ---- fallback: direct (unsorted) f32 kernel --------------------------------
__global__ __launch_bounds__(256) void voxel_hash_query_f32(
    const float* __restrict__ qpts,
    const float* __restrict__ feats0, const float* __restrict__ feats1,
    const int*   __restrict__ h2v0,   const int*   __restrict__ h2v1,
    float* __restrict__ out, int M)
{
    const int tid = blockIdx.x * blockDim.x + threadIdx.x;
    const int group = tid >> 3, gt = tid & 7;
    const int m = group >> 1, level = group & 1;
    if (m >= M) return;
    const float res = level ? RES1 : RES0;
    const float* __restrict__ feats = level ? feats1 : feats0;
    const int*   __restrict__ h2v   = level ? h2v1   : h2v0;
    const float qx = qpts[3 * (size_t)m], qy = qpts[3 * (size_t)m + 1],
                qz = qpts[3 * (size_t)m + 2];
    const float sx = qx / res, sy = qy / res, sz = qz / res;
    const float bx = floorf(sx), by = floorf(sy), bz = floorf(sz);
    const float fx = sx - bx, fy = sy - by, fz = sz - bz;
    const int ox = (gt >> 2) & 1, oy = (gt >> 1) & 1, oz = gt & 1;
    const int v = h2v[vhash((int)bx + ox, (int)by + oy, (int)bz + oz)];
    float w = (ox ? fx : 1.0f - fx) * (oy ? fy : 1.0f - fy);
    w *= (oz ? fz : 1.0f - fz);
    nfloat4 acc = {0.f, 0.f, 0.f, 0.f};
    #pragma unroll
    for (int c = 0; c < 8; ++c) {
        const int vc = __shfl(v, c, 8);
        const float wc = __shfl(w, c, 8);
        if (vc >= 0) {
            const nfloat4 f4 = ((const nfloat4*)(feats + (size_t)vc * 32))[gt];
            acc += wc * f4;
        }
    }
    ((nfloat4*)(out + (size_t)m * 64 + level * 32))[gt] = acc;
}

extern "C" void kernel_launch(void* const* d_in, const int* in_sizes, int n_in,
                              void* d_out, int out_size, void* d_ws, size_t ws_size,
                              hipStream_t stream) {
    const float* qpts   = (const float*)d_in[0];
    const float* feats0 = (const float*)d_in[1];
    const float* feats1 = (const float*)d_in[2];
    const int*   h2v0   = (const int*)d_in[3];
    const int*   h2v1   = (const int*)d_in[4];
    float* out = (float*)d_out;
    const int M = in_sizes[0] / 3;

    // dense-table bounds per level (margin 2 beyond any reachable corner)
    const float bmin[3] = {BMINX, BMINY, BMINZ};
    const float bmax[3] = {BMAXX, BMAXY, BMAXZ};
    int lo0[3], ex0[3], lo1[3], ex1[3];
    for (int d = 0; d < 3; ++d) {
        lo0[d] = (int)floorf(bmin[d] / RES0) - 2;
        ex0[d] = (int)floorf(bmax[d] / RES0) + 3 - lo0[d] + 1;
        lo1[d] = (int)floorf(bmin[d] / RES1) - 2;
        ex1[d] = (int)floorf(bmax[d] / RES1) + 3 - lo1[d] + 1;
    }
    const int D0 = ex0[0] * ex0[1] * ex0[2];
    const int D1 = ex1[0] * ex1[1] * ex1[2];

    // workspace layout (qsorted first for 16B alignment)
    char* p = (char*)d_ws;
    nfloat4* qsorted = (nfloat4*)p;        p += (size_t)M * 16;
    int* dense0 = (int*)p;                 p += (size_t)D0 * 4;
    int* dense1 = (int*)p;                 p += (size_t)D1 * 4;
    int* hist   = (int*)p;                 p += (size_t)NC * CPAD * 4;
    int* offs   = (int*)p;                 p += (size_t)NC * CPAD * 4;
    const size_t need = (size_t)(p - (char*)d_ws);

    const long long threads_needed = 16LL * M;
    const int nb = (int)((threads_needed + 255) / 256);

    if (ws_size < need) {
        voxel_hash_query_f32<<<nb, 256, 0, stream>>>(qpts, feats0, feats1,
                                                     h2v0, h2v1, out, M);
        return;
    }

    const int gA = (D0 + D1 + 255) / 256;
    build_dense<<<gA, 256, 0, stream>>>(h2v0, h2v1, dense0, dense1,
                                        lo0[0], lo0[1], lo0[2], ex0[1], ex0[2],
                                        lo1[0], lo1[1], lo1[2], ex1[1], ex1[2],
                                        D0, D1, hist);

    const int gB = (M + QPB - 1) / QPB;
    count_cells<<<gB, 256, 0, stream>>>(qpts, hist, M);
    scan_hist<<<1, 512, 0, stream>>>(hist, offs);
    scatter_queries<<<gB, 256, 0, stream>>>(qpts, offs, qsorted, M);

    const int nb8 = (nb + 7) / 8;
    voxel_query_sorted<<<nb8 * 8, 256, 0, stream>>>(
        qsorted, feats0, feats1, h2v0, h2v1, dense0, dense1,
        lo0[0], lo0[1], lo0[2], ex0[0], ex0[1], ex0[2],
        lo1[0], lo1[1], lo1[2], ex1[0], ex1[1], ex1[2],
        out, M, nb);
}